// Round 1
// baseline (6412.661 us; speedup 1.0000x reference)
//
#include <hip/hip_runtime.h>
#include <math.h>

#define SEQ 192
#define DMODEL 512
#define NTOK 24576      // 128*192
#define EPS 1e-5f

// ---------------- inverse L2 norm per token ----------------
__global__ __launch_bounds__(256) void invnorm_k(const float* __restrict__ src, float* __restrict__ invn)
{
    int w = threadIdx.x >> 6, lane = threadIdx.x & 63;
    int token = blockIdx.x * 4 + w;
    const float* p = src + (size_t)token * DMODEL;
    float s = 0.f;
#pragma unroll
    for (int i = 0; i < 8; i++) { float v = p[lane + i*64]; s += v*v; }
#pragma unroll
    for (int off = 32; off; off >>= 1) s += __shfl_xor(s, off);
    if (lane == 0) invn[token] = rsqrtf(s);
}

// ---------------- generic NT GEMM: C[m,n] = sum_k A[m,k]*B[n,k] ----------------
// A:[M,K] row-major, B:[N,K] row-major, C:[M,N]. Optional per-row scale on A,
// per-col bias, exact gelu, accumulate-into-C.
#define KT 32
__global__ __launch_bounds__(256) void gemm_nt(
    const float* __restrict__ A, const float* __restrict__ B, float* __restrict__ C,
    int N, int K, const float* __restrict__ rowscale, const float* __restrict__ bias,
    int act, int accum)
{
    __shared__ float As[KT][65];
    __shared__ float Bs[KT][65];
    int tid = threadIdx.x;
    int tx = tid & 15, ty = tid >> 4;
    int m0 = blockIdx.y * 64, n0 = blockIdx.x * 64;
    int kk = tid & 31, r = tid >> 5;
    float rs[8];
#pragma unroll
    for (int i = 0; i < 8; i++) rs[i] = rowscale ? rowscale[m0 + r + i*8] : 1.f;
    float acc[4][4] = {};
    for (int k0 = 0; k0 < K; k0 += KT) {
#pragma unroll
        for (int i = 0; i < 8; i++) {
            int row = r + i*8;
            As[kk][row] = A[(size_t)(m0+row)*K + (k0+kk)] * rs[i];
            Bs[kk][row] = B[(size_t)(n0+row)*K + (k0+kk)];
        }
        __syncthreads();
#pragma unroll
        for (int q = 0; q < KT; q++) {
            float a[4], b[4];
#pragma unroll
            for (int i=0;i<4;i++) a[i] = As[q][ty*4+i];
#pragma unroll
            for (int j=0;j<4;j++) b[j] = Bs[q][tx*4+j];
#pragma unroll
            for (int i=0;i<4;i++)
#pragma unroll
                for (int j=0;j<4;j++) acc[i][j] = fmaf(a[i], b[j], acc[i][j]);
        }
        __syncthreads();
    }
#pragma unroll
    for (int i=0;i<4;i++) {
        int m = m0 + ty*4 + i;
#pragma unroll
        for (int j=0;j<4;j++) {
            int n = n0 + tx*4 + j;
            float v = acc[i][j];
            if (bias) v += bias[n];
            if (act) v = 0.5f * v * (1.f + erff(v * 0.70710678118654752f));
            float* p = C + (size_t)m * N + n;
            if (accum) v += *p;
            *p = v;
        }
    }
}

// ---------------- exponential-decay causal conv (replaces FFT), in place on QK ----------------
// q1[t] = a*(1-a)^(h-1-t) * sum_{s<=t} (1-a)^s q[s]
__global__ __launch_bounds__(256) void decay_scan_k(float* __restrict__ QKb, const float* __restrict__ alpha)
{
    int g = blockIdx.x * 256 + threadIdx.x;   // 128*1024 threads
    int bn = g >> 10, e = g & 1023;
    float a = 1.f / (1.f + expf(-alpha[e & 63]));
    float rr = 1.f - a;
    float* p = QKb + (size_t)bn * SEQ * 1024 + e;
    float P = 0.f, pw = 1.f;
    for (int t = 0; t < SEQ; t++) {
        P += pw * p[(size_t)t*1024];
        p[(size_t)t*1024] = P;
        pw *= rr;
    }
    float f = a;
    for (int t = SEQ-1; t >= 0; t--) {
        p[(size_t)t*1024] *= f;
        f *= rr;
    }
}

// ---------------- hidden-axis attention: per (bn,nh) block ----------------
// score[e,f] = sum_t q[t,e]k[t,f]*sqrt(192); softmax over f; out[t,e] = sum_f attn[e,f] v[t,f]
__global__ __launch_bounds__(256) void hidden_attn_k(
    const float* __restrict__ QKb, const float* __restrict__ Vb, float* __restrict__ OHb)
{
    int bn = blockIdx.x >> 3, nh = blockIdx.x & 7;
    int tid = threadIdx.x;
    int e = tid & 63, fg = tid >> 6;
    __shared__ float qs[32][64];
    __shared__ float ks[32][64];
    __shared__ float at[64][65];
    float acc[16];
#pragma unroll
    for (int i=0;i<16;i++) acc[i]=0.f;
    size_t rowbase = (size_t)bn * SEQ;
    for (int a0 = 0; a0 < SEQ; a0 += 32) {
        for (int i = tid; i < 2048; i += 256) {
            int a = i >> 6, c = i & 63;
            size_t idx = (rowbase + a0 + a) * 1024 + nh*64 + c;
            qs[a][c] = QKb[idx];
            ks[a][c] = QKb[idx + 512];
        }
        __syncthreads();
#pragma unroll 8
        for (int a = 0; a < 32; a++) {
            float qv = qs[a][e];
#pragma unroll
            for (int fi = 0; fi < 16; fi++) acc[fi] = fmaf(qv, ks[a][fg*16+fi], acc[fi]);
        }
        __syncthreads();
    }
    const float sc = 13.856406460551018f; // sqrt(192)
#pragma unroll
    for (int fi = 0; fi < 16; fi++) at[e][fg*16+fi] = acc[fi] * sc;
    __syncthreads();
    if (tid < 64) {
        float m = -1e30f;
        for (int f = 0; f < 64; f++) m = fmaxf(m, at[tid][f]);
        float s = 0.f;
        for (int f = 0; f < 64; f++) { float p = expf(at[tid][f] - m); at[tid][f] = p; s += p; }
        float inv = 1.f / s;
        for (int f = 0; f < 64; f++) at[tid][f] *= inv;
    }
    __syncthreads();
    for (int a0 = 0; a0 < SEQ; a0 += 32) {
        for (int i = tid; i < 2048; i += 256) {
            int a = i >> 6, c = i & 63;
            ks[a][c] = Vb[(rowbase + a0 + a) * 512 + nh*64 + c];
        }
        __syncthreads();
#pragma unroll
        for (int rr = 0; rr < 8; rr++) {
            int a = rr*4 + fg;
            float s = 0.f;
#pragma unroll
            for (int f = 0; f < 64; f++) s = fmaf(ks[a][f], at[e][f], s);
            // reference flat order (bn, nh, t, j)
            OHb[(((size_t)bn*8 + nh)*SEQ + a0 + a)*64 + e] = s;
        }
        __syncthreads();
    }
}

// ---------------- token-axis attention: per (bn,nh) block ----------------
// score[e,f] = q1[e].k1[f]*8; softmax over f; out[e,j] = sum_f attn[e,f] v[f,j]
__global__ __launch_bounds__(256) void token_attn_k(
    const float* __restrict__ QKb, const float* __restrict__ Vb, float* __restrict__ OTb)
{
    int bn = blockIdx.x >> 3, nh = blockIdx.x & 7;
    int tid = threadIdx.x, w = tid >> 6, lane = tid & 63;
    __shared__ float k1s[192][65];   // 49.9 KB, +1 pad (64 stride would be 64-way conflict)
    __shared__ float qrow[4][64];
    __shared__ float arow[4][192];
    size_t rowbase = (size_t)bn * SEQ;
    for (int i = tid; i < 192*64; i += 256) {
        int f = i >> 6, c = i & 63;
        k1s[f][c] = QKb[(rowbase + f)*1024 + 512 + nh*64 + c];
    }
    __syncthreads();
    const float* vbase = Vb + rowbase*512 + nh*64 + lane;
    for (int r = 0; r < 48; r++) {
        int e = w*48 + r;
        qrow[w][lane] = QKb[(rowbase + e)*1024 + nh*64 + lane];
        __syncthreads();
        float s0=0.f, s1=0.f, s2=0.f;
#pragma unroll 8
        for (int c = 0; c < 64; c++) {
            float qv = qrow[w][c];
            s0 = fmaf(qv, k1s[lane][c], s0);
            s1 = fmaf(qv, k1s[lane+64][c], s1);
            s2 = fmaf(qv, k1s[lane+128][c], s2);
        }
        s0 *= 8.f; s1 *= 8.f; s2 *= 8.f;   // * hd**0.5
        float m = fmaxf(s0, fmaxf(s1, s2));
#pragma unroll
        for (int off = 32; off; off >>= 1) m = fmaxf(m, __shfl_xor(m, off));
        float p0 = expf(s0-m), p1 = expf(s1-m), p2 = expf(s2-m);
        float sum = p0+p1+p2;
#pragma unroll
        for (int off = 32; off; off >>= 1) sum += __shfl_xor(sum, off);
        float inv = 1.f / sum;
        arow[w][lane] = p0*inv; arow[w][lane+64] = p1*inv; arow[w][lane+128] = p2*inv;
        __syncthreads();
        float acc = 0.f;
#pragma unroll 4
        for (int f = 0; f < 192; f++) acc = fmaf(arow[w][f], vbase[(size_t)f*512], acc);
        OTb[(((size_t)bn*8 + nh)*SEQ + e)*64 + lane] = acc;
    }
}

// ---------------- BatchNorm: per-channel (flat%512) sums over 24576 samples ----------------
__global__ __launch_bounds__(512) void bn_stats_k(const float* __restrict__ x, float* __restrict__ st, int rowsPerBlock)
{
    int c = threadIdx.x;
    size_t r0 = (size_t)blockIdx.x * rowsPerBlock;
    float s = 0.f, q = 0.f;
    for (int r = 0; r < rowsPerBlock; r++) {
        float v = x[(r0 + r)*512 + c];
        s += v; q = fmaf(v, v, q);
    }
    atomicAdd(&st[c], s);
    atomicAdd(&st[512 + c], q);
}

__global__ __launch_bounds__(512) void residual_stats_k(float* __restrict__ y, const float* __restrict__ src,
                                                        float* __restrict__ st, int rowsPerBlock)
{
    int c = threadIdx.x;
    size_t r0 = (size_t)blockIdx.x * rowsPerBlock;
    float s = 0.f, q = 0.f;
    for (int r = 0; r < rowsPerBlock; r++) {
        size_t idx = (r0 + r)*512 + c;
        float v = y[idx] + src[idx];
        y[idx] = v;
        s += v; q = fmaf(v, v, q);
    }
    atomicAdd(&st[c], s);
    atomicAdd(&st[512 + c], q);
}

__global__ __launch_bounds__(256) void bn_apply_k(const float* __restrict__ x, const float* __restrict__ st,
    const float* __restrict__ g, const float* __restrict__ b, float* __restrict__ out)
{
    size_t i = (size_t)blockIdx.x * 256 + threadIdx.x;   // grid covers exactly 12582912
    int c = i & 511;
    float mean = st[c] * (1.f/24576.f);
    float var  = st[512+c] * (1.f/24576.f) - mean*mean;
    out[i] = (x[i] - mean) * rsqrtf(var + EPS) * g[c] + b[c];
}

extern "C" void kernel_launch(void* const* d_in, const int* in_sizes, int n_in,
                              void* d_out, int out_size, void* d_ws, size_t ws_size,
                              hipStream_t stream)
{
    const float* src    = (const float*)d_in[0];
    const float* qk_w   = (const float*)d_in[1];
    const float* qk_b   = (const float*)d_in[2];
    const float* v_w    = (const float*)d_in[3];
    const float* v_b    = (const float*)d_in[4];
    const float* alpha  = (const float*)d_in[5];
    const float* g_pre1 = (const float*)d_in[6];
    const float* b_pre1 = (const float*)d_in[7];
    const float* g_pre2 = (const float*)d_in[8];
    const float* b_pre2 = (const float*)d_in[9];
    const float* ff1_w1 = (const float*)d_in[10];
    const float* ff1_b1 = (const float*)d_in[11];
    const float* ff1_w2 = (const float*)d_in[12];
    const float* ff1_b2 = (const float*)d_in[13];
    const float* ff2_w1 = (const float*)d_in[14];
    const float* ff2_b1 = (const float*)d_in[15];
    const float* ff2_w2 = (const float*)d_in[16];
    const float* ff2_b2 = (const float*)d_in[17];
    const float* g_attn = (const float*)d_in[18];
    const float* b_attn = (const float*)d_in[19];
    float* out = (float*)d_out;

    // workspace layout (floats): total ~58.7M floats = 235 MB
    float* ws    = (float*)d_ws;
    float* invn  = ws;                                   // 24576
    float* QKb   = ws + 24576;                           // 24576*1024
    float* Vb    = QKb + (size_t)NTOK*1024;              // 24576*512
    float* OHb   = Vb  + (size_t)NTOK*512;               // 24576*512
    float* Hb    = OHb + (size_t)NTOK*512;               // 4096*2048 (FFN hidden chunk)
    float* stats = Hb  + (size_t)4096*2048;              // 3*1024

    hipMemsetAsync(stats, 0, 3*1024*sizeof(float), stream);

    // 1. norms; QK projection on normalized src (rowscale), V on raw src
    invnorm_k<<<NTOK/4, 256, 0, stream>>>(src, invn);
    gemm_nt<<<dim3(16, 384), 256, 0, stream>>>(src, qk_w, QKb, 1024, 512, invn, qk_b, 0, 0);
    gemm_nt<<<dim3(8, 384),  256, 0, stream>>>(src, v_w,  Vb,  512,  512, nullptr, v_b, 0, 0);

    // 2. hidden-axis attention on UN-decayed q,k (before in-place scan)
    hidden_attn_k<<<1024, 256, 0, stream>>>(QKb, Vb, OHb);

    // 3. decay conv (scan) in place, then token-axis attention -> OT lives in d_out
    decay_scan_k<<<512, 256, 0, stream>>>(QKb, alpha);
    token_attn_k<<<1024, 256, 0, stream>>>(QKb, Vb, out);

    // 4. BatchNorms (batch stats over all 24576 samples per channel=flat%512)
    bn_stats_k<<<192, 512, 0, stream>>>(out, stats,        128);   // out_tok -> pre2
    bn_stats_k<<<192, 512, 0, stream>>>(OHb, stats + 1024, 128);   // out_hid -> pre1
    bn_apply_k<<<49152, 256, 0, stream>>>(out, stats,        g_pre2, b_pre2, out);  // o3
    bn_apply_k<<<49152, 256, 0, stream>>>(OHb, stats + 1024, g_pre1, b_pre1, OHb);  // o2

    // 5. src2 = FF1(o3) + FF2(o2), chunked over 4096-token slabs; o3 chunk is
    //    consumed before its d_out rows are overwritten by FF1's second GEMM.
    for (int ch = 0; ch < 6; ch++) {
        float* o3c = out + (size_t)ch*4096*512;
        float* o2c = OHb + (size_t)ch*4096*512;
        gemm_nt<<<dim3(32, 64), 256, 0, stream>>>(o3c, ff1_w1, Hb,  2048, 512,  nullptr, ff1_b1, 1, 0);
        gemm_nt<<<dim3(8, 64),  256, 0, stream>>>(Hb,  ff1_w2, o3c, 512,  2048, nullptr, ff1_b2, 0, 0);
        gemm_nt<<<dim3(32, 64), 256, 0, stream>>>(o2c, ff2_w1, Hb,  2048, 512,  nullptr, ff2_b1, 1, 0);
        gemm_nt<<<dim3(8, 64),  256, 0, stream>>>(Hb,  ff2_w2, o3c, 512,  2048, nullptr, ff2_b2, 0, 1);
    }

    // 6. residual + final BN (in place on d_out)
    residual_stats_k<<<192, 512, 0, stream>>>(out, src, stats + 2048, 128);
    bn_apply_k<<<49152, 256, 0, stream>>>(out, stats + 2048, g_attn, b_attn, out);
}

// Round 2
// 1364.277 us; speedup vs baseline: 4.7004x; 4.7004x over previous
//
#include <hip/hip_runtime.h>
#include <math.h>

#define SEQ 192
#define DMODEL 512
#define NTOK 24576      // 128*192
#define EPS 1e-5f

typedef __bf16 bf16x8 __attribute__((ext_vector_type(8)));
typedef float  f32x4  __attribute__((ext_vector_type(4)));

// ---------------- inverse L2 norm per token ----------------
__global__ __launch_bounds__(256) void invnorm_k(const float* __restrict__ src, float* __restrict__ invn)
{
    int w = threadIdx.x >> 6, lane = threadIdx.x & 63;
    int token = blockIdx.x * 4 + w;
    const float* p = src + (size_t)token * DMODEL;
    float s = 0.f;
#pragma unroll
    for (int i = 0; i < 8; i++) { float v = p[lane + i*64]; s += v*v; }
#pragma unroll
    for (int off = 32; off; off >>= 1) s += __shfl_xor(s, off);
    if (lane == 0) invn[token] = rsqrtf(s);
}

// ---------------- bf16 MFMA NT GEMM: C[m,n] = sum_k A[m,k]*B[n,k] ----------------
// 128x128 block tile, 4 waves in 2x2, each wave 64x64 via 4x4 MFMA 16x16x32.
// A: f32 (convert+optional rowscale on stage) or native bf16. B: f32, converted.
// Epilogue: +bias, optional exact GELU, optional accumulate, f32 or bf16 out.
template<bool ABF16, bool GELU, bool ACCUM, bool OUTBF16>
__global__ __launch_bounds__(256) void gemm_mfma(
    const void* __restrict__ Av, const float* __restrict__ B, void* __restrict__ Cv,
    int N, int K, const float* __restrict__ rowscale, const float* __restrict__ bias)
{
    __shared__ __bf16 As[128*32];
    __shared__ __bf16 Bs[128*32];
    const int tid  = threadIdx.x;
    const int lane = tid & 63, w = tid >> 6;
    const int wr = w >> 1, wc = w & 1;
    const int m0 = blockIdx.y * 128, n0 = blockIdx.x * 128;
    const int srow = tid >> 2, sseg = tid & 3;     // each thread stages rows srow, srow+64

    float rs0 = 1.f, rs1 = 1.f;
    if (rowscale) { rs0 = rowscale[m0 + srow]; rs1 = rowscale[m0 + srow + 64]; }

    f32x4 acc[4][4];
#pragma unroll
    for (int i = 0; i < 4; i++)
#pragma unroll
        for (int j = 0; j < 4; j++) acc[i][j] = (f32x4){0.f,0.f,0.f,0.f};

    const int fr = lane & 15, fq = lane >> 4;      // fragment row-in-tile, k-quad

    for (int k0 = 0; k0 < K; k0 += 32) {
        // ---- stage A ----
        if (ABF16) {
            const __bf16* A = (const __bf16*)Av;
#pragma unroll
            for (int h = 0; h < 2; h++) {
                int r = srow + h*64;
                *(bf16x8*)&As[r*32 + sseg*8] =
                    *(const bf16x8*)&A[(size_t)(m0+r)*K + k0 + sseg*8];
            }
        } else {
            const float* A = (const float*)Av;
#pragma unroll
            for (int h = 0; h < 2; h++) {
                int r = srow + h*64;
                float rs = h ? rs1 : rs0;
                const float* p = &A[(size_t)(m0+r)*K + k0 + sseg*8];
                f32x4 a0 = *(const f32x4*)p;
                f32x4 a1 = *(const f32x4*)(p+4);
                bf16x8 v;
                v[0]=(__bf16)(a0[0]*rs); v[1]=(__bf16)(a0[1]*rs);
                v[2]=(__bf16)(a0[2]*rs); v[3]=(__bf16)(a0[3]*rs);
                v[4]=(__bf16)(a1[0]*rs); v[5]=(__bf16)(a1[1]*rs);
                v[6]=(__bf16)(a1[2]*rs); v[7]=(__bf16)(a1[3]*rs);
                *(bf16x8*)&As[r*32 + sseg*8] = v;
            }
        }
        // ---- stage B (f32 weights -> bf16) ----
#pragma unroll
        for (int h = 0; h < 2; h++) {
            int r = srow + h*64;
            const float* p = &B[(size_t)(n0+r)*K + k0 + sseg*8];
            f32x4 b0 = *(const f32x4*)p;
            f32x4 b1 = *(const f32x4*)(p+4);
            bf16x8 v;
            v[0]=(__bf16)b0[0]; v[1]=(__bf16)b0[1]; v[2]=(__bf16)b0[2]; v[3]=(__bf16)b0[3];
            v[4]=(__bf16)b1[0]; v[5]=(__bf16)b1[1]; v[6]=(__bf16)b1[2]; v[7]=(__bf16)b1[3];
            *(bf16x8*)&Bs[r*32 + sseg*8] = v;
        }
        __syncthreads();
        // ---- compute: 16 MFMAs ----
        bf16x8 af[4], bfr[4];
#pragma unroll
        for (int i = 0; i < 4; i++)
            af[i] = *(bf16x8*)&As[(wr*64 + i*16 + fr)*32 + fq*8];
#pragma unroll
        for (int j = 0; j < 4; j++)
            bfr[j] = *(bf16x8*)&Bs[(wc*64 + j*16 + fr)*32 + fq*8];
#pragma unroll
        for (int i = 0; i < 4; i++)
#pragma unroll
            for (int j = 0; j < 4; j++)
                acc[i][j] = __builtin_amdgcn_mfma_f32_16x16x32_bf16(af[i], bfr[j], acc[i][j], 0, 0, 0);
        __syncthreads();
    }
    // ---- epilogue: D row = (lane>>4)*4 + reg, col = lane&15 ----
    const int r4 = lane >> 4, cc = lane & 15;
#pragma unroll
    for (int i = 0; i < 4; i++) {
#pragma unroll
        for (int r = 0; r < 4; r++) {
            int m = m0 + wr*64 + i*16 + r4*4 + r;
#pragma unroll
            for (int j = 0; j < 4; j++) {
                int n = n0 + wc*64 + j*16 + cc;
                float v = acc[i][j][r];
                if (bias) v += bias[n];
                if (GELU) v = 0.5f * v * (1.f + erff(v * 0.70710678118654752f));
                if (OUTBF16) {
                    __bf16* C = (__bf16*)Cv;
                    C[(size_t)m * N + n] = (__bf16)v;
                } else {
                    float* C = (float*)Cv;
                    float* p = C + (size_t)m * N + n;
                    if (ACCUM) v += *p;
                    *p = v;
                }
            }
        }
    }
}

// ---------------- exponential-decay causal conv (replaces FFT), in place on QK ----------------
__global__ __launch_bounds__(256) void decay_scan_k(float* __restrict__ QKb, const float* __restrict__ alpha)
{
    int g = blockIdx.x * 256 + threadIdx.x;   // 128*1024 threads
    int bn = g >> 10, e = g & 1023;
    float a = 1.f / (1.f + expf(-alpha[e & 63]));
    float rr = 1.f - a;
    float* p = QKb + (size_t)bn * SEQ * 1024 + e;
    float P = 0.f, pw = 1.f;
    for (int t = 0; t < SEQ; t++) {
        P += pw * p[(size_t)t*1024];
        p[(size_t)t*1024] = P;
        pw *= rr;
    }
    float f = a;
    for (int t = SEQ-1; t >= 0; t--) {
        p[(size_t)t*1024] *= f;
        f *= rr;
    }
}

// ---------------- hidden-axis attention: per (bn,nh) block ----------------
__global__ __launch_bounds__(256) void hidden_attn_k(
    const float* __restrict__ QKb, const float* __restrict__ Vb, float* __restrict__ OHb)
{
    int bn = blockIdx.x >> 3, nh = blockIdx.x & 7;
    int tid = threadIdx.x;
    int e = tid & 63, fg = tid >> 6;
    __shared__ float qs[32][64];
    __shared__ float ks[32][64];
    __shared__ float at[64][65];
    float acc[16];
#pragma unroll
    for (int i=0;i<16;i++) acc[i]=0.f;
    size_t rowbase = (size_t)bn * SEQ;
    for (int a0 = 0; a0 < SEQ; a0 += 32) {
        for (int i = tid; i < 2048; i += 256) {
            int a = i >> 6, c = i & 63;
            size_t idx = (rowbase + a0 + a) * 1024 + nh*64 + c;
            qs[a][c] = QKb[idx];
            ks[a][c] = QKb[idx + 512];
        }
        __syncthreads();
#pragma unroll 8
        for (int a = 0; a < 32; a++) {
            float qv = qs[a][e];
#pragma unroll
            for (int fi = 0; fi < 16; fi++) acc[fi] = fmaf(qv, ks[a][fg*16+fi], acc[fi]);
        }
        __syncthreads();
    }
    const float sc = 13.856406460551018f; // sqrt(192)
#pragma unroll
    for (int fi = 0; fi < 16; fi++) at[e][fg*16+fi] = acc[fi] * sc;
    __syncthreads();
    if (tid < 64) {
        float m = -1e30f;
        for (int f = 0; f < 64; f++) m = fmaxf(m, at[tid][f]);
        float s = 0.f;
        for (int f = 0; f < 64; f++) { float p = expf(at[tid][f] - m); at[tid][f] = p; s += p; }
        float inv = 1.f / s;
        for (int f = 0; f < 64; f++) at[tid][f] *= inv;
    }
    __syncthreads();
    for (int a0 = 0; a0 < SEQ; a0 += 32) {
        for (int i = tid; i < 2048; i += 256) {
            int a = i >> 6, c = i & 63;
            ks[a][c] = Vb[(rowbase + a0 + a) * 512 + nh*64 + c];
        }
        __syncthreads();
#pragma unroll
        for (int rr = 0; rr < 8; rr++) {
            int a = rr*4 + fg;
            float s = 0.f;
#pragma unroll
            for (int f = 0; f < 64; f++) s = fmaf(ks[a][f], at[e][f], s);
            OHb[(((size_t)bn*8 + nh)*SEQ + a0 + a)*64 + e] = s;
        }
        __syncthreads();
    }
}

// ---------------- token-axis attention: flash-style, one e-row per thread ----------------
// block = (bn, nh), 192 threads (3 waves); q row + O accumulator in VGPRs;
// K1/V 32-row tiles in LDS read as wave-uniform broadcasts (conflict-free).
__global__ __launch_bounds__(192) void token_attn2_k(
    const float* __restrict__ QKb, const float* __restrict__ Vb, float* __restrict__ OTb)
{
    int bn = blockIdx.x >> 3, nh = blockIdx.x & 7;
    int tid = threadIdx.x;                 // e row 0..191
    __shared__ float ks[32][68];           // stride 68: keeps 16B alignment for b128
    __shared__ float vs[32][68];
    size_t rowbase = (size_t)bn * SEQ;

    float q[64];
    const float* qp = QKb + (rowbase + tid)*1024 + nh*64;
#pragma unroll
    for (int d = 0; d < 64; d++) q[d] = qp[d];

    float m = -1e30f, l = 0.f;
    float O[64];
#pragma unroll
    for (int d = 0; d < 64; d++) O[d] = 0.f;

    for (int f0 = 0; f0 < SEQ; f0 += 32) {
        __syncthreads();
        for (int i = tid; i < 2048; i += 192) {
            int f = i >> 6, c = i & 63;
            ks[f][c] = QKb[(rowbase + f0 + f)*1024 + 512 + nh*64 + c];
            vs[f][c] = Vb[(rowbase + f0 + f)*512 + nh*64 + c];
        }
        __syncthreads();
        float s[32];
#pragma unroll
        for (int f = 0; f < 32; f++) {
            float a = 0.f;
#pragma unroll
            for (int d = 0; d < 64; d++) a = fmaf(q[d], ks[f][d], a);
            s[f] = a * 8.f;                // * hd**0.5
        }
        float mt = m;
#pragma unroll
        for (int f = 0; f < 32; f++) mt = fmaxf(mt, s[f]);
        float alpha = __expf(m - mt);
        m = mt;
        l *= alpha;
#pragma unroll
        for (int d = 0; d < 64; d++) O[d] *= alpha;
#pragma unroll
        for (int f = 0; f < 32; f++) {
            float p = __expf(s[f] - m);
            l += p;
#pragma unroll
            for (int d = 0; d < 64; d++) O[d] = fmaf(p, vs[f][d], O[d]);
        }
    }
    float inv = 1.f / l;
    float* op = OTb + (((size_t)bn*8 + nh)*SEQ + tid)*64;
#pragma unroll
    for (int d = 0; d < 64; d++) op[d] = O[d] * inv;
}

// ---------------- BatchNorm: per-channel (flat%512) sums over 24576 samples ----------------
__global__ __launch_bounds__(512) void bn_stats_k(const float* __restrict__ x, float* __restrict__ st, int rowsPerBlock)
{
    int c = threadIdx.x;
    size_t r0 = (size_t)blockIdx.x * rowsPerBlock;
    float s = 0.f, q = 0.f;
    for (int r = 0; r < rowsPerBlock; r++) {
        float v = x[(r0 + r)*512 + c];
        s += v; q = fmaf(v, v, q);
    }
    atomicAdd(&st[c], s);
    atomicAdd(&st[512 + c], q);
}

__global__ __launch_bounds__(512) void residual_stats_k(float* __restrict__ y, const float* __restrict__ src,
                                                        float* __restrict__ st, int rowsPerBlock)
{
    int c = threadIdx.x;
    size_t r0 = (size_t)blockIdx.x * rowsPerBlock;
    float s = 0.f, q = 0.f;
    for (int r = 0; r < rowsPerBlock; r++) {
        size_t idx = (r0 + r)*512 + c;
        float v = y[idx] + src[idx];
        y[idx] = v;
        s += v; q = fmaf(v, v, q);
    }
    atomicAdd(&st[c], s);
    atomicAdd(&st[512 + c], q);
}

__global__ __launch_bounds__(256) void bn_apply_k(const float* __restrict__ x, const float* __restrict__ st,
    const float* __restrict__ g, const float* __restrict__ b, float* __restrict__ out)
{
    size_t i = (size_t)blockIdx.x * 256 + threadIdx.x;
    int c = i & 511;
    float mean = st[c] * (1.f/24576.f);
    float var  = st[512+c] * (1.f/24576.f) - mean*mean;
    out[i] = (x[i] - mean) * rsqrtf(var + EPS) * g[c] + b[c];
}

__global__ __launch_bounds__(256) void bn_apply_bf16_k(const float* __restrict__ x, const float* __restrict__ st,
    const float* __restrict__ g, const float* __restrict__ b, __bf16* __restrict__ out)
{
    size_t i = (size_t)blockIdx.x * 256 + threadIdx.x;
    int c = i & 511;
    float mean = st[c] * (1.f/24576.f);
    float var  = st[512+c] * (1.f/24576.f) - mean*mean;
    out[i] = (__bf16)((x[i] - mean) * rsqrtf(var + EPS) * g[c] + b[c]);
}

extern "C" void kernel_launch(void* const* d_in, const int* in_sizes, int n_in,
                              void* d_out, int out_size, void* d_ws, size_t ws_size,
                              hipStream_t stream)
{
    const float* src    = (const float*)d_in[0];
    const float* qk_w   = (const float*)d_in[1];
    const float* qk_b   = (const float*)d_in[2];
    const float* v_w    = (const float*)d_in[3];
    const float* v_b    = (const float*)d_in[4];
    const float* alpha  = (const float*)d_in[5];
    const float* g_pre1 = (const float*)d_in[6];
    const float* b_pre1 = (const float*)d_in[7];
    const float* g_pre2 = (const float*)d_in[8];
    const float* b_pre2 = (const float*)d_in[9];
    const float* ff1_w1 = (const float*)d_in[10];
    const float* ff1_b1 = (const float*)d_in[11];
    const float* ff1_w2 = (const float*)d_in[12];
    const float* ff1_b2 = (const float*)d_in[13];
    const float* ff2_w1 = (const float*)d_in[14];
    const float* ff2_b1 = (const float*)d_in[15];
    const float* ff2_w2 = (const float*)d_in[16];
    const float* ff2_b2 = (const float*)d_in[17];
    const float* g_attn = (const float*)d_in[18];
    const float* b_attn = (const float*)d_in[19];
    float* out = (float*)d_out;

    // workspace (floats): invn | QKb 24576x1024 | Vb 24576x512 | OHb 24576x512 | stats
    // After token_attn: QKb region reused as Hb (bf16 24576x2048, exact fit),
    //                   Vb region reused as o3_bf + o2_bf (bf16 24576x512 each, exact fit).
    float* ws    = (float*)d_ws;
    float* invn  = ws;                                    // 24576
    float* QKb   = ws + 24576;                            // 25165824 f
    float* Vb    = QKb + (size_t)NTOK*1024;               // 12582912 f
    float* OHb   = Vb  + (size_t)NTOK*512;                // 12582912 f
    float* stats = OHb + (size_t)NTOK*512;                // 3072 f
    __bf16* Hb   = (__bf16*)QKb;                          // 24576x2048 bf16
    __bf16* o3bf = (__bf16*)Vb;                           // 24576x512 bf16
    __bf16* o2bf = o3bf + (size_t)NTOK*512;               // 24576x512 bf16

    hipMemsetAsync(stats, 0, 3*1024*sizeof(float), stream);

    // 1. norms; QK projection (rowscale=invn) and V projection, bf16 MFMA
    invnorm_k<<<NTOK/4, 256, 0, stream>>>(src, invn);
    gemm_mfma<false,false,false,false><<<dim3(8, 192), 256, 0, stream>>>(src, qk_w, QKb, 1024, 512, invn, qk_b);
    gemm_mfma<false,false,false,false><<<dim3(4, 192), 256, 0, stream>>>(src, v_w,  Vb,  512,  512, nullptr, v_b);

    // 2. hidden-axis attention on UN-decayed q,k
    hidden_attn_k<<<1024, 256, 0, stream>>>(QKb, Vb, OHb);

    // 3. decay conv (scan) in place, then flash token attention -> d_out
    decay_scan_k<<<512, 256, 0, stream>>>(QKb, alpha);
    token_attn2_k<<<1024, 192, 0, stream>>>(QKb, Vb, out);

    // 4. BatchNorms -> bf16 activations for FFN
    bn_stats_k<<<768, 512, 0, stream>>>(out, stats,        32);   // out_tok -> pre2
    bn_stats_k<<<768, 512, 0, stream>>>(OHb, stats + 1024, 32);   // out_hid -> pre1
    bn_apply_bf16_k<<<49152, 256, 0, stream>>>(out, stats,        g_pre2, b_pre2, o3bf);  // o3
    bn_apply_bf16_k<<<49152, 256, 0, stream>>>(OHb, stats + 1024, g_pre1, b_pre1, o2bf);  // o2

    // 5. src2 = FF1(o3) + FF2(o2); hidden stored bf16 in old QKb region
    gemm_mfma<true, true, false,true ><<<dim3(16, 192), 256, 0, stream>>>(o3bf, ff1_w1, Hb,  2048, 512,  nullptr, ff1_b1);
    gemm_mfma<true, false,false,false><<<dim3(4, 192),  256, 0, stream>>>(Hb,   ff1_w2, out, 512,  2048, nullptr, ff1_b2);
    gemm_mfma<true, true, false,true ><<<dim3(16, 192), 256, 0, stream>>>(o2bf, ff2_w1, Hb,  2048, 512,  nullptr, ff2_b1);
    gemm_mfma<true, false,true, false><<<dim3(4, 192),  256, 0, stream>>>(Hb,   ff2_w2, out, 512,  2048, nullptr, ff2_b2);

    // 6. residual + final BN (in place on d_out)
    residual_stats_k<<<768, 512, 0, stream>>>(out, src, stats + 2048, 32);
    bn_apply_k<<<49152, 256, 0, stream>>>(out, stats + 2048, g_attn, b_attn, out);
}

// Round 3
// 1005.755 us; speedup vs baseline: 6.3760x; 1.3565x over previous
//
#include <hip/hip_runtime.h>
#include <math.h>

#define SEQ 192
#define NTOK 24576      // 128*192
#define EPS 1e-5f

typedef __bf16 bf16x8 __attribute__((ext_vector_type(8)));
typedef __bf16 bf16x4 __attribute__((ext_vector_type(4)));
typedef float  f32x4  __attribute__((ext_vector_type(4)));

__device__ __forceinline__ void load_lds16(const __bf16* g, __bf16* l) {
    __builtin_amdgcn_global_load_lds(
        (const __attribute__((address_space(1))) uint32_t*)g,
        (__attribute__((address_space(3))) uint32_t*)l, 16, 0, 0);
}

// ---------------- f32 -> bf16 bulk convert (weights) ----------------
__global__ __launch_bounds__(256) void cvt_k(const float* __restrict__ x, __bf16* __restrict__ y)
{
    int i = blockIdx.x * 256 + threadIdx.x;
    f32x4 v = ((const f32x4*)x)[i];
    bf16x4 o;
    o[0]=(__bf16)v[0]; o[1]=(__bf16)v[1]; o[2]=(__bf16)v[2]; o[3]=(__bf16)v[3];
    ((bf16x4*)y)[i] = o;
}

// ---------------- prep: src -> bf16 raw + bf16 L2-normalized ----------------
__global__ __launch_bounds__(256) void prep_k(const float* __restrict__ src,
    __bf16* __restrict__ srcb, __bf16* __restrict__ srcnb)
{
    int w = threadIdx.x >> 6, lane = threadIdx.x & 63;
    size_t token = blockIdx.x * 4 + w;
    const float* p = src + token * 512 + lane * 8;
    f32x4 a0 = *(const f32x4*)p;
    f32x4 a1 = *(const f32x4*)(p + 4);
    float s = a0[0]*a0[0]+a0[1]*a0[1]+a0[2]*a0[2]+a0[3]*a0[3]
            + a1[0]*a1[0]+a1[1]*a1[1]+a1[2]*a1[2]+a1[3]*a1[3];
#pragma unroll
    for (int off = 32; off; off >>= 1) s += __shfl_xor(s, off);
    float rs = rsqrtf(s);
    bf16x8 vb, vn;
#pragma unroll
    for (int q = 0; q < 4; q++) {
        vb[q]   = (__bf16)a0[q];      vn[q]   = (__bf16)(a0[q]*rs);
        vb[q+4] = (__bf16)a1[q];      vn[q+4] = (__bf16)(a1[q]*rs);
    }
    *(bf16x8*)&srcb[token*512 + lane*8]  = vb;
    *(bf16x8*)&srcnb[token*512 + lane*8] = vn;
}

// ---------------- bf16 MFMA NT GEMM, global_load_lds staging ----------------
// C[m,n] = sum_k A[m,k]*B[n,k]; 128x128 tile, 4 waves 2x2, 16x16x32 MFMA.
template<bool GELU, bool ACCUM, bool OUTBF16>
__global__ __launch_bounds__(256) void gemm_bb_k(
    const __bf16* __restrict__ A, const __bf16* __restrict__ B, void* __restrict__ Cv,
    int N, int K, const float* __restrict__ bias)
{
    __shared__ __bf16 As[4096];
    __shared__ __bf16 Bs[4096];
    const int tid = threadIdx.x, lane = tid & 63, w = tid >> 6;
    const int wr = w >> 1, wc = w & 1;
    const int m0 = blockIdx.y * 128, n0 = blockIdx.x * 128;
    const int srow = tid >> 2, sseg = tid & 3;
    const int fr = lane & 15, fq = lane >> 4;
    const __bf16* ga = A + (size_t)(m0 + srow) * K + sseg * 8;
    const __bf16* gb = B + (size_t)(n0 + srow) * K + sseg * 8;
    __bf16* la = &As[tid * 8];
    __bf16* lb = &Bs[tid * 8];
    f32x4 acc[4][4];
#pragma unroll
    for (int i = 0; i < 4; i++)
#pragma unroll
        for (int j = 0; j < 4; j++) acc[i][j] = (f32x4){0.f,0.f,0.f,0.f};

    for (int k0 = 0; k0 < K; k0 += 32) {
        load_lds16(ga + k0,                 la);
        load_lds16(ga + k0 + (size_t)64*K,  la + 2048);
        load_lds16(gb + k0,                 lb);
        load_lds16(gb + k0 + (size_t)64*K,  lb + 2048);
        __syncthreads();
        bf16x8 af[4], bf[4];
#pragma unroll
        for (int i = 0; i < 4; i++)
            af[i] = *(bf16x8*)&As[(wr*64 + i*16 + fr)*32 + fq*8];
#pragma unroll
        for (int j = 0; j < 4; j++)
            bf[j] = *(bf16x8*)&Bs[(wc*64 + j*16 + fr)*32 + fq*8];
#pragma unroll
        for (int i = 0; i < 4; i++)
#pragma unroll
            for (int j = 0; j < 4; j++)
                acc[i][j] = __builtin_amdgcn_mfma_f32_16x16x32_bf16(af[i], bf[j], acc[i][j], 0, 0, 0);
        __syncthreads();
    }
    const int r4 = lane >> 4, cc = lane & 15;
#pragma unroll
    for (int i = 0; i < 4; i++) {
#pragma unroll
        for (int r = 0; r < 4; r++) {
            int m = m0 + wr*64 + i*16 + r4*4 + r;
#pragma unroll
            for (int j = 0; j < 4; j++) {
                int n = n0 + wc*64 + j*16 + cc;
                float v = acc[i][j][r];
                if (bias) v += bias[n];
                if (GELU) v = 0.5f * v * (1.f + erff(v * 0.70710678118654752f));
                if (OUTBF16) {
                    ((__bf16*)Cv)[(size_t)m * N + n] = (__bf16)v;
                } else {
                    float* p = (float*)Cv + (size_t)m * N + n;
                    if (ACCUM) v += *p;
                    *p = v;
                }
            }
        }
    }
}

// ---------------- exponential-decay causal scan (replaces FFT), in place, bf16 ----------------
__global__ __launch_bounds__(256) void decay_scan_k(__bf16* __restrict__ QKb, const float* __restrict__ alpha)
{
    int g = blockIdx.x * 256 + threadIdx.x;   // 131072 threads
    int bn = g >> 10, e = g & 1023;
    float a = 1.f / (1.f + expf(-alpha[e & 63]));
    float rr = 1.f - a;
    __bf16* p = QKb + (size_t)bn * SEQ * 1024 + e;
    float P = 0.f, pw = 1.f;
    for (int t = 0; t < SEQ; t++) {
        P += pw * (float)p[(size_t)t*1024];
        p[(size_t)t*1024] = (__bf16)P;
        pw *= rr;
    }
    float f = a;
    for (int t = SEQ-1; t >= 0; t--) {
        p[(size_t)t*1024] = (__bf16)((float)p[(size_t)t*1024] * f);
        f *= rr;
    }
}

// ---------------- hidden-axis attention, MFMA. block=(bn,nh), 256 thr ----------------
// S[e,f]=sum_t q[t,e]k[t,f]*sqrt(192); softmax over f; O[t,e]=sum_f P[e,f]v[t,f]
__global__ __launch_bounds__(256) void hidden_attn_mfma_k(
    const __bf16* __restrict__ QKb, const __bf16* __restrict__ Vb, float* __restrict__ OHb)
{
    __shared__ __bf16 smem[25600];
    __bf16* Qt = smem;             // 64 x 200 (phase 1)  [e][t]
    __bf16* Kt = smem + 12800;     // 64 x 200            [f][t]
    __bf16* Ps = smem;             // 64 x 72  (phase 2)  [e][f]
    __bf16* Vs = smem + 4608;      // 192 x 72            [t][f]
    const int bn = blockIdx.x >> 3, nh = blockIdx.x & 7;
    const int tid = threadIdx.x, lane = tid & 63, w = tid >> 6;
    const int fr = lane & 15, fq = lane >> 4;
    const size_t rowbase = (size_t)bn * SEQ;

    for (int i = tid; i < 12288; i += 256) {          // transpose-stage q^T,k^T
        int t = i >> 6, j = i & 63;
        const __bf16* g = QKb + (rowbase + t)*1024 + nh*64 + j;
        Qt[j*200 + t] = g[0];
        Kt[j*200 + t] = g[512];
    }
    __syncthreads();

    f32x4 acc[4];
#pragma unroll
    for (int i = 0; i < 4; i++) acc[i] = (f32x4){0.f,0.f,0.f,0.f};
#pragma unroll
    for (int kc = 0; kc < 6; kc++) {
        bf16x8 a = *(bf16x8*)&Qt[(w*16 + fr)*200 + kc*32 + fq*8];
#pragma unroll
        for (int nt = 0; nt < 4; nt++) {
            bf16x8 b = *(bf16x8*)&Kt[(nt*16 + fr)*200 + kc*32 + fq*8];
            acc[nt] = __builtin_amdgcn_mfma_f32_16x16x32_bf16(a, b, acc[nt], 0, 0, 0);
        }
    }
    const float sc = 13.856406460551018f;   // sqrt(192)
    float pn[4][4];
#pragma unroll
    for (int reg = 0; reg < 4; reg++) {
        float m = -1e30f;
#pragma unroll
        for (int nt = 0; nt < 4; nt++) { acc[nt][reg] *= sc; m = fmaxf(m, acc[nt][reg]); }
#pragma unroll
        for (int off = 1; off < 16; off <<= 1) m = fmaxf(m, __shfl_xor(m, off));
        float l = 0.f;
#pragma unroll
        for (int nt = 0; nt < 4; nt++) { pn[nt][reg] = __expf(acc[nt][reg] - m); l += pn[nt][reg]; }
#pragma unroll
        for (int off = 1; off < 16; off <<= 1) l += __shfl_xor(l, off);
        float inv = 1.f / l;
#pragma unroll
        for (int nt = 0; nt < 4; nt++) pn[nt][reg] *= inv;
    }
    __syncthreads();                                   // Qt/Kt dead
#pragma unroll
    for (int nt = 0; nt < 4; nt++)
#pragma unroll
        for (int reg = 0; reg < 4; reg++)
            Ps[(w*16 + fq*4 + reg)*72 + nt*16 + fr] = (__bf16)pn[nt][reg];
    for (int i = tid; i < 1536; i += 256) {            // stage V natural
        int t = i >> 3, s = i & 7;
        *(bf16x8*)&Vs[t*72 + s*8] = *(const bf16x8*)&Vb[(rowbase+t)*512 + nh*64 + s*8];
    }
    __syncthreads();

    f32x4 o[3][4];
#pragma unroll
    for (int i = 0; i < 3; i++)
#pragma unroll
        for (int j = 0; j < 4; j++) o[i][j] = (f32x4){0.f,0.f,0.f,0.f};
#pragma unroll
    for (int kc = 0; kc < 2; kc++) {
        bf16x8 av[3];
#pragma unroll
        for (int mt = 0; mt < 3; mt++)
            av[mt] = *(bf16x8*)&Vs[(48*w + mt*16 + fr)*72 + kc*32 + fq*8];
#pragma unroll
        for (int nt = 0; nt < 4; nt++) {
            bf16x8 b = *(bf16x8*)&Ps[(nt*16 + fr)*72 + kc*32 + fq*8];
#pragma unroll
            for (int mt = 0; mt < 3; mt++)
                o[mt][nt] = __builtin_amdgcn_mfma_f32_16x16x32_bf16(av[mt], b, o[mt][nt], 0, 0, 0);
        }
    }
    float* obase = OHb + ((size_t)(bn*8 + nh)) * SEQ * 64;
#pragma unroll
    for (int mt = 0; mt < 3; mt++)
#pragma unroll
        for (int reg = 0; reg < 4; reg++) {
            int t = 48*w + mt*16 + fq*4 + reg;
#pragma unroll
            for (int nt = 0; nt < 4; nt++)
                obase[(size_t)t*64 + nt*16 + fr] = o[mt][nt][reg];
        }
}

// ---------------- token-axis attention, MFMA. block=(bn,nh), 256 thr ----------------
// S[e,f]=q1[e].k1[f]*8; softmax over f; O[e,d]=sum_f P[e,f]v[f,d]
__global__ __launch_bounds__(256) void token_attn_mfma_k(
    const __bf16* __restrict__ QKb, const __bf16* __restrict__ Vb, float* __restrict__ OT)
{
    __shared__ __bf16 smem[27648];
    __bf16* Qs = smem;              // 192 x 72 (phase A) [e][d]
    __bf16* Ks = smem + 13824;      // 192 x 72           [f][d]
    __bf16* Vt = smem;              // 64 x 200 (phase B) [d][f]
    __bf16* Pw = smem + 12800;      // 4 waves x (48 x 72)
    const int bn = blockIdx.x >> 3, nh = blockIdx.x & 7;
    const int tid = threadIdx.x, lane = tid & 63, w = tid >> 6;
    const int fr = lane & 15, fq = lane >> 4;
    const size_t rowbase = (size_t)bn * SEQ;

    for (int i = tid; i < 1536; i += 256) {
        int t = i >> 3, s = i & 7;
        const __bf16* g = QKb + (rowbase + t)*1024 + nh*64;
        *(bf16x8*)&Qs[t*72 + s*8] = *(const bf16x8*)&g[s*8];
        *(bf16x8*)&Ks[t*72 + s*8] = *(const bf16x8*)&g[512 + s*8];
    }
    __syncthreads();

    f32x4 S[3][12];
#pragma unroll
    for (int i = 0; i < 3; i++)
#pragma unroll
        for (int j = 0; j < 12; j++) S[i][j] = (f32x4){0.f,0.f,0.f,0.f};
#pragma unroll
    for (int kc = 0; kc < 2; kc++) {
        bf16x8 aq[3];
#pragma unroll
        for (int mt = 0; mt < 3; mt++)
            aq[mt] = *(bf16x8*)&Qs[(48*w + mt*16 + fr)*72 + kc*32 + fq*8];
#pragma unroll
        for (int nt = 0; nt < 12; nt++) {
            bf16x8 b = *(bf16x8*)&Ks[(nt*16 + fr)*72 + kc*32 + fq*8];
#pragma unroll
            for (int mt = 0; mt < 3; mt++)
                S[mt][nt] = __builtin_amdgcn_mfma_f32_16x16x32_bf16(aq[mt], b, S[mt][nt], 0, 0, 0);
        }
    }
    // softmax: row e = 48w + mt*16 + fq*4 + reg, cols = nt*16 + fr
#pragma unroll
    for (int mt = 0; mt < 3; mt++)
#pragma unroll
        for (int reg = 0; reg < 4; reg++) {
            float m = -1e30f;
#pragma unroll
            for (int nt = 0; nt < 12; nt++) { S[mt][nt][reg] *= 8.f; m = fmaxf(m, S[mt][nt][reg]); }
#pragma unroll
            for (int off = 1; off < 16; off <<= 1) m = fmaxf(m, __shfl_xor(m, off));
            float l = 0.f;
#pragma unroll
            for (int nt = 0; nt < 12; nt++) { S[mt][nt][reg] = __expf(S[mt][nt][reg] - m); l += S[mt][nt][reg]; }
#pragma unroll
            for (int off = 1; off < 16; off <<= 1) l += __shfl_xor(l, off);
            float inv = 1.f / l;
#pragma unroll
            for (int nt = 0; nt < 12; nt++) S[mt][nt][reg] *= inv;
        }
    __syncthreads();                                   // Qs/Ks dead
    for (int i = tid; i < 12288; i += 256) {           // transpose-stage V^T
        int t = i >> 6, d = i & 63;
        Vt[d*200 + t] = Vb[(rowbase + t)*512 + nh*64 + d];
    }
    __syncthreads();

    f32x4 O[3][4];
#pragma unroll
    for (int i = 0; i < 3; i++)
#pragma unroll
        for (int j = 0; j < 4; j++) O[i][j] = (f32x4){0.f,0.f,0.f,0.f};
    __bf16* myP = Pw + w*3456;
#pragma unroll
    for (int fc = 0; fc < 3; fc++) {
#pragma unroll
        for (int mt = 0; mt < 3; mt++)
#pragma unroll
            for (int j = 0; j < 4; j++)
#pragma unroll
                for (int reg = 0; reg < 4; reg++)
                    myP[(mt*16 + fq*4 + reg)*72 + j*16 + fr] = (__bf16)S[mt][fc*4 + j][reg];
        // per-wave LDS region; DS ops are in-order per wave -> no barrier needed
#pragma unroll
        for (int kc = 0; kc < 2; kc++) {
            bf16x8 ap[3];
#pragma unroll
            for (int mt = 0; mt < 3; mt++)
                ap[mt] = *(bf16x8*)&myP[(mt*16 + fr)*72 + kc*32 + fq*8];
#pragma unroll
            for (int dt = 0; dt < 4; dt++) {
                bf16x8 b = *(bf16x8*)&Vt[(dt*16 + fr)*200 + fc*64 + kc*32 + fq*8];
#pragma unroll
                for (int mt = 0; mt < 3; mt++)
                    O[mt][dt] = __builtin_amdgcn_mfma_f32_16x16x32_bf16(ap[mt], b, O[mt][dt], 0, 0, 0);
            }
        }
    }
    float* obase = OT + ((size_t)(bn*8 + nh)) * SEQ * 64;
#pragma unroll
    for (int mt = 0; mt < 3; mt++)
#pragma unroll
        for (int reg = 0; reg < 4; reg++) {
            int e = 48*w + mt*16 + fq*4 + reg;
#pragma unroll
            for (int dt = 0; dt < 4; dt++)
                obase[(size_t)e*64 + dt*16 + fr] = O[mt][dt][reg];
        }
}

// ---------------- BatchNorm helpers (channel = flat % 512) ----------------
__global__ __launch_bounds__(512) void bn_stats_k(const float* __restrict__ x, float* __restrict__ st, int rowsPerBlock)
{
    int c = threadIdx.x;
    size_t r0 = (size_t)blockIdx.x * rowsPerBlock;
    float s = 0.f, q = 0.f;
    for (int r = 0; r < rowsPerBlock; r++) {
        float v = x[(r0 + r)*512 + c];
        s += v; q = fmaf(v, v, q);
    }
    atomicAdd(&st[c], s);
    atomicAdd(&st[512 + c], q);
}

__global__ __launch_bounds__(512) void residual_stats_k(float* __restrict__ y, const float* __restrict__ src,
                                                        float* __restrict__ st, int rowsPerBlock)
{
    int c = threadIdx.x;
    size_t r0 = (size_t)blockIdx.x * rowsPerBlock;
    float s = 0.f, q = 0.f;
    for (int r = 0; r < rowsPerBlock; r++) {
        size_t idx = (r0 + r)*512 + c;
        float v = y[idx] + src[idx];
        y[idx] = v;
        s += v; q = fmaf(v, v, q);
    }
    atomicAdd(&st[c], s);
    atomicAdd(&st[512 + c], q);
}

__global__ __launch_bounds__(256) void bn_apply_k(const float* __restrict__ x, const float* __restrict__ st,
    const float* __restrict__ g, const float* __restrict__ b, float* __restrict__ out)
{
    size_t i = (size_t)blockIdx.x * 256 + threadIdx.x;
    int c = i & 511;
    float mean = st[c] * (1.f/24576.f);
    float var  = st[512+c] * (1.f/24576.f) - mean*mean;
    out[i] = (x[i] - mean) * rsqrtf(var + EPS) * g[c] + b[c];
}

__global__ __launch_bounds__(256) void bn_apply_bf16_k(const float* __restrict__ x, const float* __restrict__ st,
    const float* __restrict__ g, const float* __restrict__ b, __bf16* __restrict__ out)
{
    size_t i = (size_t)blockIdx.x * 256 + threadIdx.x;
    int c = i & 511;
    float mean = st[c] * (1.f/24576.f);
    float var  = st[512+c] * (1.f/24576.f) - mean*mean;
    out[i] = (__bf16)((x[i] - mean) * rsqrtf(var + EPS) * g[c] + b[c]);
}

extern "C" void kernel_launch(void* const* d_in, const int* in_sizes, int n_in,
                              void* d_out, int out_size, void* d_ws, size_t ws_size,
                              hipStream_t stream)
{
    const float* src    = (const float*)d_in[0];
    const float* qk_w   = (const float*)d_in[1];
    const float* qk_b   = (const float*)d_in[2];
    const float* v_w    = (const float*)d_in[3];
    const float* v_b    = (const float*)d_in[4];
    const float* alpha  = (const float*)d_in[5];
    const float* g_pre1 = (const float*)d_in[6];
    const float* b_pre1 = (const float*)d_in[7];
    const float* g_pre2 = (const float*)d_in[8];
    const float* b_pre2 = (const float*)d_in[9];
    const float* ff1_w1 = (const float*)d_in[10];
    const float* ff1_b1 = (const float*)d_in[11];
    const float* ff1_w2 = (const float*)d_in[12];
    const float* ff1_b2 = (const float*)d_in[13];
    const float* ff2_w1 = (const float*)d_in[14];
    const float* ff2_b1 = (const float*)d_in[15];
    const float* ff2_w2 = (const float*)d_in[16];
    const float* ff2_b2 = (const float*)d_in[17];
    const float* g_attn = (const float*)d_in[18];
    const float* b_attn = (const float*)d_in[19];
    float* out = (float*)d_out;

    // ws layout (bf16 elements unless noted), ~211 MB total:
    __bf16* wb   = (__bf16*)d_ws;
    __bf16* wq   = wb;                                  //  524288
    __bf16* wv   = wq  + 524288;                        //  262144
    __bf16* w11  = wv  + 262144;                        // 1048576
    __bf16* w12  = w11 + 1048576;                       // 1048576
    __bf16* w21  = w12 + 1048576;                       // 1048576
    __bf16* w22  = w21 + 1048576;                       // 1048576
    __bf16* srcb  = w22 + 1048576;                      // 12582912
    __bf16* srcnb = srcb + (size_t)NTOK*512;            // 12582912
    __bf16* QKb   = srcnb + (size_t)NTOK*512;           // 25165824
    __bf16* Vb    = QKb + (size_t)NTOK*1024;            // 12582912
    float*  OHb   = (float*)(Vb + (size_t)NTOK*512);    // 12582912 f32
    __bf16* Hext  = (__bf16*)(OHb + (size_t)NTOK*512);  // 12582912
    float*  stats = (float*)(Hext + (size_t)NTOK*512);  // 3072 f32
    __bf16* Hb    = Vb;            // FFN hidden 24576x2048 spans Vb+OHb+Hext (exact)
    __bf16* o3bf  = QKb;           // post-BN acts live in dead QKb region
    __bf16* o2bf  = QKb + (size_t)NTOK*512;

    hipMemsetAsync(stats, 0, 3*1024*sizeof(float), stream);

    // 0. one-time bf16 conversions
    cvt_k<<<512,  256, 0, stream>>>(qk_w,   wq);
    cvt_k<<<256,  256, 0, stream>>>(v_w,    wv);
    cvt_k<<<1024, 256, 0, stream>>>(ff1_w1, w11);
    cvt_k<<<1024, 256, 0, stream>>>(ff1_w2, w12);
    cvt_k<<<1024, 256, 0, stream>>>(ff2_w1, w21);
    cvt_k<<<1024, 256, 0, stream>>>(ff2_w2, w22);
    prep_k<<<NTOK/4, 256, 0, stream>>>(src, srcb, srcnb);

    // 1. projections (bf16 in, bf16 out)
    gemm_bb_k<false,false,true><<<dim3(8, 192), 256, 0, stream>>>(srcnb, wq, QKb, 1024, 512, qk_b);
    gemm_bb_k<false,false,true><<<dim3(4, 192), 256, 0, stream>>>(srcb,  wv, Vb,  512,  512, v_b);

    // 2. hidden-axis attention on UN-decayed q,k
    hidden_attn_mfma_k<<<1024, 256, 0, stream>>>(QKb, Vb, OHb);

    // 3. decay scan in place, then MFMA token attention -> d_out (f32)
    decay_scan_k<<<512, 256, 0, stream>>>(QKb, alpha);
    token_attn_mfma_k<<<1024, 256, 0, stream>>>(QKb, Vb, out);

    // 4. BatchNorms -> bf16 activations for FFN
    bn_stats_k<<<768, 512, 0, stream>>>(out, stats,        32);   // out_tok -> pre2
    bn_stats_k<<<768, 512, 0, stream>>>(OHb, stats + 1024, 32);   // out_hid -> pre1
    bn_apply_bf16_k<<<49152, 256, 0, stream>>>(out, stats,        g_pre2, b_pre2, o3bf);
    bn_apply_bf16_k<<<49152, 256, 0, stream>>>(OHb, stats + 1024, g_pre1, b_pre1, o2bf);

    // 5. src2 = FF1(o3) + FF2(o2)
    gemm_bb_k<true, false,true ><<<dim3(16, 192), 256, 0, stream>>>(o3bf, w11, Hb,  2048, 512,  ff1_b1);
    gemm_bb_k<false,false,false><<<dim3(4, 192),  256, 0, stream>>>(Hb,   w12, out, 512,  2048, ff1_b2);
    gemm_bb_k<true, false,true ><<<dim3(16, 192), 256, 0, stream>>>(o2bf, w21, Hb,  2048, 512,  ff2_b1);
    gemm_bb_k<false,true, false><<<dim3(4, 192),  256, 0, stream>>>(Hb,   w22, out, 512,  2048, ff2_b2);

    // 6. residual + final BN (in place on d_out)
    residual_stats_k<<<768, 512, 0, stream>>>(out, src, stats + 2048, 32);
    bn_apply_k<<<49152, 256, 0, stream>>>(out, stats + 2048, g_attn, b_attn, out);
}

// Round 4
// 910.143 us; speedup vs baseline: 7.0458x; 1.1051x over previous
//
#include <hip/hip_runtime.h>
#include <math.h>

#define SEQ 192
#define NTOK 24576      // 128*192
#define EPS 1e-5f

typedef __bf16 bf16x8 __attribute__((ext_vector_type(8)));
typedef __bf16 bf16x4 __attribute__((ext_vector_type(4)));
typedef float  f32x4  __attribute__((ext_vector_type(4)));

__device__ __forceinline__ void load_lds16(const __bf16* g, __bf16* l) {
    __builtin_amdgcn_global_load_lds(
        (const __attribute__((address_space(1))) uint32_t*)g,
        (__attribute__((address_space(3))) uint32_t*)l, 16, 0, 0);
}

// tanh-form GELU via sigmoid: x*sigmoid(1.5958*(x+0.044715 x^3)); ~8 VALU ops
__device__ __forceinline__ float gelu_f(float x) {
    float z = 1.5957691216057308f * x * fmaf(0.044715f, x*x, 1.f);
    float e = __expf(-z);
    return x * __builtin_amdgcn_rcpf(1.f + e);
}

// ---------------- f32 -> bf16 bulk convert (weights) ----------------
__global__ __launch_bounds__(256) void cvt_k(const float* __restrict__ x, __bf16* __restrict__ y)
{
    int i = blockIdx.x * 256 + threadIdx.x;
    f32x4 v = ((const f32x4*)x)[i];
    bf16x4 o;
    o[0]=(__bf16)v[0]; o[1]=(__bf16)v[1]; o[2]=(__bf16)v[2]; o[3]=(__bf16)v[3];
    ((bf16x4*)y)[i] = o;
}

// ---------------- prep: src -> bf16 raw + bf16 L2-normalized ----------------
__global__ __launch_bounds__(256) void prep_k(const float* __restrict__ src,
    __bf16* __restrict__ srcb, __bf16* __restrict__ srcnb)
{
    int w = threadIdx.x >> 6, lane = threadIdx.x & 63;
    size_t token = blockIdx.x * 4 + w;
    const float* p = src + token * 512 + lane * 8;
    f32x4 a0 = *(const f32x4*)p;
    f32x4 a1 = *(const f32x4*)(p + 4);
    float s = a0[0]*a0[0]+a0[1]*a0[1]+a0[2]*a0[2]+a0[3]*a0[3]
            + a1[0]*a1[0]+a1[1]*a1[1]+a1[2]*a1[2]+a1[3]*a1[3];
#pragma unroll
    for (int off = 32; off; off >>= 1) s += __shfl_xor(s, off);
    float rs = rsqrtf(s);
    bf16x8 vb, vn;
#pragma unroll
    for (int q = 0; q < 4; q++) {
        vb[q]   = (__bf16)a0[q];      vn[q]   = (__bf16)(a0[q]*rs);
        vb[q+4] = (__bf16)a1[q];      vn[q+4] = (__bf16)(a1[q]*rs);
    }
    *(bf16x8*)&srcb[token*512 + lane*8]  = vb;
    *(bf16x8*)&srcnb[token*512 + lane*8] = vn;
}

// ---------------- bf16 MFMA NT GEMM, BK=64, XOR-swizzled LDS ----------------
// C[m,n] = sum_k A[m,k]*B[n,k]; 128x128 tile, 4 waves 2x2, 16x16x32 MFMA.
// AMODE 0: A bf16 via global_load_lds.  AMODE 1: A f32 + per-column BN affine
//          (coef[0:512]=scale, coef[512:1024]=shift), K must be 512.
// EPI 0: f32 store. 1: bf16 store. 2: f32 accumulate + residual + BN stats.
template<int AMODE, bool GELU, int EPI>
__global__ __launch_bounds__(256) void gemm_k(
    const void* __restrict__ Av, const __bf16* __restrict__ B, void* __restrict__ Cv,
    int N, int K, const float* __restrict__ bias,
    const float* __restrict__ coef, const float* __restrict__ resid, float* __restrict__ st)
{
    __shared__ __bf16 As[8192];   // [128][64], row stride 128B, seg XOR-swizzled
    __shared__ __bf16 Bs[8192];
    const int tid = threadIdx.x, lane = tid & 63, w = tid >> 6;
    const int wr = w >> 1, wc = w & 1;
    const int m0 = blockIdx.y * 128, n0 = blockIdx.x * 128;
    const int fr = lane & 15, fq = lane >> 4;
    // staging: chunk = 8 rows = 1KB contiguous; lane fetches swizzled column seg
    const int grow = 8*w + (lane >> 3);
    const int gcol = ((lane & 7) ^ (lane >> 3)) * 8;
    const __bf16* gB = B + (size_t)(n0 + grow) * K + gcol;
    const __bf16* gA = (AMODE == 0) ? ((const __bf16*)Av + (size_t)(m0 + grow) * K + gcol) : nullptr;
    __bf16* ldsA = As + 8*w*64 + lane*8;
    __bf16* ldsB = Bs + 8*w*64 + lane*8;

    f32x4 acc[4][4];
#pragma unroll
    for (int i = 0; i < 4; i++)
#pragma unroll
        for (int j = 0; j < 4; j++) acc[i][j] = (f32x4){0.f,0.f,0.f,0.f};

    for (int k0 = 0; k0 < K; k0 += 64) {
        if (AMODE == 0) {
#pragma unroll
            for (int i = 0; i < 4; i++)
                load_lds16(gA + k0 + (size_t)(32*i)*K, ldsA + i*2048);
        } else {
            const float* A = (const float*)Av;
            const int r = tid >> 3, cseg = tid & 7;
            const float* scp = coef + k0 + cseg*8;
            const float* shp = coef + 512 + k0 + cseg*8;
            f32x4 sc0 = *(const f32x4*)scp, sc1 = *(const f32x4*)(scp+4);
            f32x4 sh0 = *(const f32x4*)shp, sh1 = *(const f32x4*)(shp+4);
#pragma unroll
            for (int i = 0; i < 4; i++) {
                int row = 32*i + r;
                const float* p = A + (size_t)(m0+row)*512 + k0 + cseg*8;
                f32x4 a0 = *(const f32x4*)p, a1 = *(const f32x4*)(p+4);
                bf16x8 v;
#pragma unroll
                for (int q = 0; q < 4; q++) {
                    v[q]   = (__bf16)fmaf(a0[q], sc0[q], sh0[q]);
                    v[q+4] = (__bf16)fmaf(a1[q], sc1[q], sh1[q]);
                }
                *(bf16x8*)&As[row*64 + ((cseg ^ (r & 7)) * 8)] = v;
            }
        }
#pragma unroll
        for (int i = 0; i < 4; i++)
            load_lds16(gB + k0 + (size_t)(32*i)*K, ldsB + i*2048);
        __syncthreads();
#pragma unroll
        for (int kk = 0; kk < 2; kk++) {
            bf16x8 af[4], bfv[4];
#pragma unroll
            for (int i = 0; i < 4; i++)
                af[i] = *(bf16x8*)&As[(wr*64 + i*16 + fr)*64 + (((kk*4+fq) ^ (fr&7))*8)];
#pragma unroll
            for (int j = 0; j < 4; j++)
                bfv[j] = *(bf16x8*)&Bs[(wc*64 + j*16 + fr)*64 + (((kk*4+fq) ^ (fr&7))*8)];
#pragma unroll
            for (int i = 0; i < 4; i++)
#pragma unroll
                for (int j = 0; j < 4; j++)
                    acc[i][j] = __builtin_amdgcn_mfma_f32_16x16x32_bf16(af[i], bfv[j], acc[i][j], 0, 0, 0);
        }
        __syncthreads();
    }
    // epilogue: C row = r4*4 + reg (r4=lane>>4), col = lane&15
    const int r4 = lane >> 4, cc = lane & 15;
    float cs[4] = {0,0,0,0}, cq[4] = {0,0,0,0};
#pragma unroll
    for (int i = 0; i < 4; i++) {
#pragma unroll
        for (int r = 0; r < 4; r++) {
            int m = m0 + wr*64 + i*16 + r4*4 + r;
#pragma unroll
            for (int j = 0; j < 4; j++) {
                int n = n0 + wc*64 + j*16 + cc;
                float v = acc[i][j][r] + bias[n];
                if (GELU) v = gelu_f(v);
                if (EPI == 1) {
                    ((__bf16*)Cv)[(size_t)m * N + n] = (__bf16)v;
                } else if (EPI == 0) {
                    ((float*)Cv)[(size_t)m * N + n] = v;
                } else {
                    size_t idx = (size_t)m * N + n;
                    v += ((float*)Cv)[idx] + resid[idx];
                    ((float*)Cv)[idx] = v;
                    cs[j] += v; cq[j] = fmaf(v, v, cq[j]);
                }
            }
        }
    }
    if (EPI == 2) {
#pragma unroll
        for (int j = 0; j < 4; j++) {
            cs[j] += __shfl_xor(cs[j], 16); cs[j] += __shfl_xor(cs[j], 32);
            cq[j] += __shfl_xor(cq[j], 16); cq[j] += __shfl_xor(cq[j], 32);
        }
        if (r4 == 0) {
#pragma unroll
            for (int j = 0; j < 4; j++) {
                int n = n0 + wc*64 + j*16 + cc;
                atomicAdd(&st[n], cs[j]);
                atomicAdd(&st[512 + n], cq[j]);
            }
        }
    }
}

// ---------------- exponential-decay causal scan (replaces FFT), in place, bf16 ----------------
__global__ __launch_bounds__(256) void decay_scan_k(__bf16* __restrict__ QKb, const float* __restrict__ alpha)
{
    int g = blockIdx.x * 256 + threadIdx.x;   // 131072 threads
    int bn = g >> 10, e = g & 1023;
    float a = 1.f / (1.f + expf(-alpha[e & 63]));
    float rr = 1.f - a;
    __bf16* p = QKb + (size_t)bn * SEQ * 1024 + e;
    float P = 0.f, pw = 1.f;
    for (int t = 0; t < SEQ; t++) {
        P += pw * (float)p[(size_t)t*1024];
        p[(size_t)t*1024] = (__bf16)P;
        pw *= rr;
    }
    float f = a;
    for (int t = SEQ-1; t >= 0; t--) {
        p[(size_t)t*1024] = (__bf16)((float)p[(size_t)t*1024] * f);
        f *= rr;
    }
}

// ---------------- hidden-axis attention, MFMA. block=(bn,nh), 256 thr ----------------
__global__ __launch_bounds__(256) void hidden_attn_mfma_k(
    const __bf16* __restrict__ QKb, const __bf16* __restrict__ Vb, float* __restrict__ OHb)
{
    __shared__ __bf16 smem[25600];
    __bf16* Qt = smem;             // 64 x 200 (phase 1)  [e][t]
    __bf16* Kt = smem + 12800;     // 64 x 200            [f][t]
    __bf16* Ps = smem;             // 64 x 72  (phase 2)  [e][f]
    __bf16* Vs = smem + 4608;      // 192 x 72            [t][f]
    const int bn = blockIdx.x >> 3, nh = blockIdx.x & 7;
    const int tid = threadIdx.x, lane = tid & 63, w = tid >> 6;
    const int fr = lane & 15, fq = lane >> 4;
    const size_t rowbase = (size_t)bn * SEQ;

    for (int i = tid; i < 12288; i += 256) {          // transpose-stage q^T,k^T
        int t = i >> 6, j = i & 63;
        const __bf16* g = QKb + (rowbase + t)*1024 + nh*64 + j;
        Qt[j*200 + t] = g[0];
        Kt[j*200 + t] = g[512];
    }
    __syncthreads();

    f32x4 acc[4];
#pragma unroll
    for (int i = 0; i < 4; i++) acc[i] = (f32x4){0.f,0.f,0.f,0.f};
#pragma unroll
    for (int kc = 0; kc < 6; kc++) {
        bf16x8 a = *(bf16x8*)&Qt[(w*16 + fr)*200 + kc*32 + fq*8];
#pragma unroll
        for (int nt = 0; nt < 4; nt++) {
            bf16x8 b = *(bf16x8*)&Kt[(nt*16 + fr)*200 + kc*32 + fq*8];
            acc[nt] = __builtin_amdgcn_mfma_f32_16x16x32_bf16(a, b, acc[nt], 0, 0, 0);
        }
    }
    const float sc = 13.856406460551018f;   // sqrt(192)
    float pn[4][4];
#pragma unroll
    for (int reg = 0; reg < 4; reg++) {
        float m = -1e30f;
#pragma unroll
        for (int nt = 0; nt < 4; nt++) { acc[nt][reg] *= sc; m = fmaxf(m, acc[nt][reg]); }
#pragma unroll
        for (int off = 1; off < 16; off <<= 1) m = fmaxf(m, __shfl_xor(m, off));
        float l = 0.f;
#pragma unroll
        for (int nt = 0; nt < 4; nt++) { pn[nt][reg] = __expf(acc[nt][reg] - m); l += pn[nt][reg]; }
#pragma unroll
        for (int off = 1; off < 16; off <<= 1) l += __shfl_xor(l, off);
        float inv = 1.f / l;
#pragma unroll
        for (int nt = 0; nt < 4; nt++) pn[nt][reg] *= inv;
    }
    __syncthreads();                                   // Qt/Kt dead
#pragma unroll
    for (int nt = 0; nt < 4; nt++)
#pragma unroll
        for (int reg = 0; reg < 4; reg++)
            Ps[(w*16 + fq*4 + reg)*72 + nt*16 + fr] = (__bf16)pn[nt][reg];
    for (int i = tid; i < 1536; i += 256) {            // stage V natural
        int t = i >> 3, s = i & 7;
        *(bf16x8*)&Vs[t*72 + s*8] = *(const bf16x8*)&Vb[(rowbase+t)*512 + nh*64 + s*8];
    }
    __syncthreads();

    f32x4 o[3][4];
#pragma unroll
    for (int i = 0; i < 3; i++)
#pragma unroll
        for (int j = 0; j < 4; j++) o[i][j] = (f32x4){0.f,0.f,0.f,0.f};
#pragma unroll
    for (int kc = 0; kc < 2; kc++) {
        bf16x8 av[3];
#pragma unroll
        for (int mt = 0; mt < 3; mt++)
            av[mt] = *(bf16x8*)&Vs[(48*w + mt*16 + fr)*72 + kc*32 + fq*8];
#pragma unroll
        for (int nt = 0; nt < 4; nt++) {
            bf16x8 b = *(bf16x8*)&Ps[(nt*16 + fr)*72 + kc*32 + fq*8];
#pragma unroll
            for (int mt = 0; mt < 3; mt++)
                o[mt][nt] = __builtin_amdgcn_mfma_f32_16x16x32_bf16(av[mt], b, o[mt][nt], 0, 0, 0);
        }
    }
    float* obase = OHb + ((size_t)(bn*8 + nh)) * SEQ * 64;
#pragma unroll
    for (int mt = 0; mt < 3; mt++)
#pragma unroll
        for (int reg = 0; reg < 4; reg++) {
            int t = 48*w + mt*16 + fq*4 + reg;
#pragma unroll
            for (int nt = 0; nt < 4; nt++)
                obase[(size_t)t*64 + nt*16 + fr] = o[mt][nt][reg];
        }
}

// ---------------- token-axis attention, MFMA. block=(bn,nh), 256 thr ----------------
__global__ __launch_bounds__(256) void token_attn_mfma_k(
    const __bf16* __restrict__ QKb, const __bf16* __restrict__ Vb, float* __restrict__ OT)
{
    __shared__ __bf16 smem[27648];
    __bf16* Qs = smem;              // 192 x 72 (phase A) [e][d]
    __bf16* Ks = smem + 13824;      // 192 x 72           [f][d]
    __bf16* Vt = smem;              // 64 x 200 (phase B) [d][f]
    __bf16* Pw = smem + 12800;      // 4 waves x (48 x 72)
    const int bn = blockIdx.x >> 3, nh = blockIdx.x & 7;
    const int tid = threadIdx.x, lane = tid & 63, w = tid >> 6;
    const int fr = lane & 15, fq = lane >> 4;
    const size_t rowbase = (size_t)bn * SEQ;

    for (int i = tid; i < 1536; i += 256) {
        int t = i >> 3, s = i & 7;
        const __bf16* g = QKb + (rowbase + t)*1024 + nh*64;
        *(bf16x8*)&Qs[t*72 + s*8] = *(const bf16x8*)&g[s*8];
        *(bf16x8*)&Ks[t*72 + s*8] = *(const bf16x8*)&g[512 + s*8];
    }
    __syncthreads();

    f32x4 S[3][12];
#pragma unroll
    for (int i = 0; i < 3; i++)
#pragma unroll
        for (int j = 0; j < 12; j++) S[i][j] = (f32x4){0.f,0.f,0.f,0.f};
#pragma unroll
    for (int kc = 0; kc < 2; kc++) {
        bf16x8 aq[3];
#pragma unroll
        for (int mt = 0; mt < 3; mt++)
            aq[mt] = *(bf16x8*)&Qs[(48*w + mt*16 + fr)*72 + kc*32 + fq*8];
#pragma unroll
        for (int nt = 0; nt < 12; nt++) {
            bf16x8 b = *(bf16x8*)&Ks[(nt*16 + fr)*72 + kc*32 + fq*8];
#pragma unroll
            for (int mt = 0; mt < 3; mt++)
                S[mt][nt] = __builtin_amdgcn_mfma_f32_16x16x32_bf16(aq[mt], b, S[mt][nt], 0, 0, 0);
        }
    }
#pragma unroll
    for (int mt = 0; mt < 3; mt++)
#pragma unroll
        for (int reg = 0; reg < 4; reg++) {
            float m = -1e30f;
#pragma unroll
            for (int nt = 0; nt < 12; nt++) { S[mt][nt][reg] *= 8.f; m = fmaxf(m, S[mt][nt][reg]); }
#pragma unroll
            for (int off = 1; off < 16; off <<= 1) m = fmaxf(m, __shfl_xor(m, off));
            float l = 0.f;
#pragma unroll
            for (int nt = 0; nt < 12; nt++) { S[mt][nt][reg] = __expf(S[mt][nt][reg] - m); l += S[mt][nt][reg]; }
#pragma unroll
            for (int off = 1; off < 16; off <<= 1) l += __shfl_xor(l, off);
            float inv = 1.f / l;
#pragma unroll
            for (int nt = 0; nt < 12; nt++) S[mt][nt][reg] *= inv;
        }
    __syncthreads();                                   // Qs/Ks dead
    for (int i = tid; i < 12288; i += 256) {           // transpose-stage V^T
        int t = i >> 6, d = i & 63;
        Vt[d*200 + t] = Vb[(rowbase + t)*512 + nh*64 + d];
    }
    __syncthreads();

    f32x4 O[3][4];
#pragma unroll
    for (int i = 0; i < 3; i++)
#pragma unroll
        for (int j = 0; j < 4; j++) O[i][j] = (f32x4){0.f,0.f,0.f,0.f};
    __bf16* myP = Pw + w*3456;
#pragma unroll
    for (int fc = 0; fc < 3; fc++) {
#pragma unroll
        for (int mt = 0; mt < 3; mt++)
#pragma unroll
            for (int j = 0; j < 4; j++)
#pragma unroll
                for (int reg = 0; reg < 4; reg++)
                    myP[(mt*16 + fq*4 + reg)*72 + j*16 + fr] = (__bf16)S[mt][fc*4 + j][reg];
        // per-wave LDS region; DS ops are in-order per wave -> no barrier needed
#pragma unroll
        for (int kc = 0; kc < 2; kc++) {
            bf16x8 ap[3];
#pragma unroll
            for (int mt = 0; mt < 3; mt++)
                ap[mt] = *(bf16x8*)&myP[(mt*16 + fr)*72 + kc*32 + fq*8];
#pragma unroll
            for (int dt = 0; dt < 4; dt++) {
                bf16x8 b = *(bf16x8*)&Vt[(dt*16 + fr)*200 + fc*64 + kc*32 + fq*8];
#pragma unroll
                for (int mt = 0; mt < 3; mt++)
                    O[mt][dt] = __builtin_amdgcn_mfma_f32_16x16x32_bf16(ap[mt], b, O[mt][dt], 0, 0, 0);
            }
        }
    }
    float* obase = OT + ((size_t)(bn*8 + nh)) * SEQ * 64;
#pragma unroll
    for (int mt = 0; mt < 3; mt++)
#pragma unroll
        for (int reg = 0; reg < 4; reg++) {
            int e = 48*w + mt*16 + fq*4 + reg;
#pragma unroll
            for (int dt = 0; dt < 4; dt++)
                obase[(size_t)e*64 + dt*16 + fr] = O[mt][dt][reg];
        }
}

// ---------------- BatchNorm helpers (channel = flat % 512), vectorized x4 ----------------
__global__ __launch_bounds__(256) void bn_stats4_k(const float* __restrict__ x, float* __restrict__ st)
{
    int col4 = threadIdx.x & 127;
    int rowblk = blockIdx.x * 2 + (threadIdx.x >> 7);   // grid 384 -> 768 rowblks x 32 rows
    const f32x4* p = (const f32x4*)x + (size_t)rowblk*32*128 + col4;
    float s[4] = {0,0,0,0}, q[4] = {0,0,0,0};
    for (int r = 0; r < 32; r++) {
        f32x4 v = p[(size_t)r*128];
#pragma unroll
        for (int j = 0; j < 4; j++) { s[j] += v[j]; q[j] = fmaf(v[j], v[j], q[j]); }
    }
#pragma unroll
    for (int j = 0; j < 4; j++) {
        atomicAdd(&st[col4*4 + j], s[j]);
        atomicAdd(&st[512 + col4*4 + j], q[j]);
    }
}

__global__ void bn_coef_k(const float* __restrict__ st, const float* __restrict__ g,
                          const float* __restrict__ b, float* __restrict__ coef)
{
    int c = threadIdx.x;   // 512
    float mean = st[c] * (1.f/24576.f);
    float var  = st[512+c] * (1.f/24576.f) - mean*mean;
    float sc = rsqrtf(var + EPS) * g[c];
    coef[c] = sc;
    coef[512 + c] = b[c] - mean * sc;
}

__global__ __launch_bounds__(256) void bn_apply_bf164_k(const float* __restrict__ x, const float* __restrict__ st,
    const float* __restrict__ g, const float* __restrict__ b, __bf16* __restrict__ out)
{
    size_t i = (size_t)blockIdx.x * 256 + threadIdx.x;   // 12288 blocks
    int col4 = i & 127;
    f32x4 v = ((const f32x4*)x)[i];
    f32x4 sm = ((const f32x4*)st)[col4];
    f32x4 sq = ((const f32x4*)(st + 512))[col4];
    bf16x4 o;
#pragma unroll
    for (int j = 0; j < 4; j++) {
        int c = col4*4 + j;
        float mean = sm[j] * (1.f/24576.f);
        float var  = sq[j] * (1.f/24576.f) - mean*mean;
        o[j] = (__bf16)((v[j] - mean) * rsqrtf(var + EPS) * g[c] + b[c]);
    }
    ((bf16x4*)out)[i] = o;
}

__global__ __launch_bounds__(256) void bn_apply4_k(const float* __restrict__ x, const float* __restrict__ st,
    const float* __restrict__ g, const float* __restrict__ b, float* __restrict__ out)
{
    size_t i = (size_t)blockIdx.x * 256 + threadIdx.x;   // 12288 blocks
    int col4 = i & 127;
    f32x4 v = ((const f32x4*)x)[i];
    f32x4 sm = ((const f32x4*)st)[col4];
    f32x4 sq = ((const f32x4*)(st + 512))[col4];
    f32x4 o;
#pragma unroll
    for (int j = 0; j < 4; j++) {
        int c = col4*4 + j;
        float mean = sm[j] * (1.f/24576.f);
        float var  = sq[j] * (1.f/24576.f) - mean*mean;
        o[j] = (v[j] - mean) * rsqrtf(var + EPS) * g[c] + b[c];
    }
    ((f32x4*)out)[i] = o;
}

extern "C" void kernel_launch(void* const* d_in, const int* in_sizes, int n_in,
                              void* d_out, int out_size, void* d_ws, size_t ws_size,
                              hipStream_t stream)
{
    const float* src    = (const float*)d_in[0];
    const float* qk_w   = (const float*)d_in[1];
    const float* qk_b   = (const float*)d_in[2];
    const float* v_w    = (const float*)d_in[3];
    const float* v_b    = (const float*)d_in[4];
    const float* alpha  = (const float*)d_in[5];
    const float* g_pre1 = (const float*)d_in[6];
    const float* b_pre1 = (const float*)d_in[7];
    const float* g_pre2 = (const float*)d_in[8];
    const float* b_pre2 = (const float*)d_in[9];
    const float* ff1_w1 = (const float*)d_in[10];
    const float* ff1_b1 = (const float*)d_in[11];
    const float* ff1_w2 = (const float*)d_in[12];
    const float* ff1_b2 = (const float*)d_in[13];
    const float* ff2_w1 = (const float*)d_in[14];
    const float* ff2_b1 = (const float*)d_in[15];
    const float* ff2_w2 = (const float*)d_in[16];
    const float* ff2_b2 = (const float*)d_in[17];
    const float* g_attn = (const float*)d_in[18];
    const float* b_attn = (const float*)d_in[19];
    float* out = (float*)d_out;

    // ws layout (same footprint as R3 + 1K floats of coef):
    __bf16* wb   = (__bf16*)d_ws;
    __bf16* wq   = wb;                                  //  524288
    __bf16* wv   = wq  + 524288;                        //  262144
    __bf16* w11  = wv  + 262144;                        // 1048576
    __bf16* w12  = w11 + 1048576;                       // 1048576
    __bf16* w21  = w12 + 1048576;                       // 1048576
    __bf16* w22  = w21 + 1048576;                       // 1048576
    __bf16* srcb  = w22 + 1048576;                      // 12582912
    __bf16* srcnb = srcb + (size_t)NTOK*512;            // 12582912
    __bf16* QKb   = srcnb + (size_t)NTOK*512;           // 25165824
    __bf16* Vb    = QKb + (size_t)NTOK*1024;            // 12582912
    float*  OHb   = (float*)(Vb + (size_t)NTOK*512);    // 12582912 f32
    __bf16* Hext  = (__bf16*)(OHb + (size_t)NTOK*512);  // 12582912
    float*  stats = (float*)(Hext + (size_t)NTOK*512);  // 3072 f32
    float*  coef0 = stats + 3072;                       // 1024 f32
    __bf16* Hb    = Vb;            // FFN hidden 24576x2048 spans Vb+OHb+Hext (exact)
    __bf16* o2bf  = QKb;           // post-BN o2 lives in dead QKb region
    float*  st0 = stats, *st1 = stats + 1024, *st2 = stats + 2048;

    hipMemsetAsync(stats, 0, 3*1024*sizeof(float), stream);

    // 0. one-time bf16 conversions
    cvt_k<<<512,  256, 0, stream>>>(qk_w,   wq);
    cvt_k<<<256,  256, 0, stream>>>(v_w,    wv);
    cvt_k<<<1024, 256, 0, stream>>>(ff1_w1, w11);
    cvt_k<<<1024, 256, 0, stream>>>(ff1_w2, w12);
    cvt_k<<<1024, 256, 0, stream>>>(ff2_w1, w21);
    cvt_k<<<1024, 256, 0, stream>>>(ff2_w2, w22);
    prep_k<<<NTOK/4, 256, 0, stream>>>(src, srcb, srcnb);

    // 1. projections
    gemm_k<0,false,1><<<dim3(8, 192), 256, 0, stream>>>(srcnb, wq, QKb, 1024, 512, qk_b, nullptr, nullptr, nullptr);
    gemm_k<0,false,1><<<dim3(4, 192), 256, 0, stream>>>(srcb,  wv, Vb,  512,  512, v_b,  nullptr, nullptr, nullptr);

    // 2. hidden-axis attention on UN-decayed q,k
    hidden_attn_mfma_k<<<1024, 256, 0, stream>>>(QKb, Vb, OHb);

    // 3. decay scan in place, then MFMA token attention -> d_out (f32)
    decay_scan_k<<<512, 256, 0, stream>>>(QKb, alpha);
    token_attn_mfma_k<<<1024, 256, 0, stream>>>(QKb, Vb, out);

    // 4. BN stats; o3-BN folds into FF1-W1 staging (coef0); o2 materialized bf16
    bn_stats4_k<<<384, 256, 0, stream>>>(out, st0);    // out_tok -> pre2
    bn_stats4_k<<<384, 256, 0, stream>>>(OHb, st1);    // out_hid -> pre1
    bn_coef_k<<<1, 512, 0, stream>>>(st0, g_pre2, b_pre2, coef0);
    bn_apply_bf164_k<<<12288, 256, 0, stream>>>(OHb, st1, g_pre1, b_pre1, o2bf);

    // 5. src2 = FF1(o3) + FF2(o2); FF2-W2 fuses +src residual and final-BN stats
    gemm_k<1,true, 1><<<dim3(16, 192), 256, 0, stream>>>(out,  w11, Hb,  2048, 512,  ff1_b1, coef0, nullptr, nullptr);
    gemm_k<0,false,0><<<dim3(4, 192),  256, 0, stream>>>(Hb,   w12, out, 512,  2048, ff1_b2, nullptr, nullptr, nullptr);
    gemm_k<0,true, 1><<<dim3(16, 192), 256, 0, stream>>>(o2bf, w21, Hb,  2048, 512,  ff2_b1, nullptr, nullptr, nullptr);
    gemm_k<0,false,2><<<dim3(4, 192),  256, 0, stream>>>(Hb,   w22, out, 512,  2048, ff2_b2, nullptr, src, st2);

    // 6. final BN (in place on d_out)
    bn_apply4_k<<<12288, 256, 0, stream>>>(out, st2, g_attn, b_attn, out);
}